// Round 3
// baseline (4577.325 us; speedup 1.0000x reference)
//
#include <hip/hip_runtime.h>
#include <math.h>

// Problem constants (fixed by setup_inputs: B=8, S=2048, din=dhid=1024)
#define B_   8
#define S_   2048
#define D_   1024
#define M_   (B_ * S_)    // 16384 rows total
#define K2_  (2 * D_)     // 2048 = concat(inp, pe) width

// ---------------------------------------------------------------------------
// ws layout (floats), chunked by c batches (c chosen from ws_size at launch):
//   pe      [S_][D_]          @ 0
//   bufQV   [c*S_][D_]        q, later v (reused within chunk)
//   bufK    [c*S_][D_]        k
//   scoresT [c][S_][S_]
// bytes = 8 MiB + c * 32 MiB   (c=8 -> 264 MiB ... c=1 -> 40 MiB)
// ---------------------------------------------------------------------------

// ============================ pe table (float64) ===========================
__global__ __launch_bounds__(256) void pe_fill(float* __restrict__ pe) {
    const int s  = blockIdx.x;
    const int j0 = threadIdx.x * 4;
#pragma unroll
    for (int e = 0; e < 4; ++e) {
        int j = j0 + e;
        double ex = (double)(2 * (j >> 1)) / (double)D_;
        double dv = pow(10000.0, ex);
        double a  = (double)s / dv;
        float val;
        if (s == 0) val = 0.0f;
        else        val = (j & 1) ? (float)cos(a) : (float)sin(a);
        pe[s * D_ + j] = val;
    }
}

// ======================= shared GEMM building blocks =======================
// Tile: 128x128, BK=16, 256 threads, 8x8 micro-tile per thread.
// As/Bs are [16][132] (pad 4 floats keeps float4 alignment, breaks bank stride)

__device__ __forceinline__ void stage_trans(const float* __restrict__ src,
                                            int ld, int row0, int k0,
                                            float (*T)[132], int tid) {
    // src rows are the M/N dim, cols the K dim -> store transposed T[k][row]
#pragma unroll
    for (int it = 0; it < 2; ++it) {
        int f  = tid + it * 256;      // 512 float4s = 128 rows x 4 float4
        int r  = f >> 2;
        int c4 = (f & 3) << 2;
        float4 v = *(const float4*)&src[(size_t)(row0 + r) * ld + k0 + c4];
        T[c4 + 0][r] = v.x;
        T[c4 + 1][r] = v.y;
        T[c4 + 2][r] = v.z;
        T[c4 + 3][r] = v.w;
    }
}

__device__ __forceinline__ void stage_direct(const float* __restrict__ src,
                                             int ld, int k0, int col0,
                                             float (*T)[132], int tid) {
    // src rows are the K dim -> straight copy T[k][col]
#pragma unroll
    for (int it = 0; it < 2; ++it) {
        int f  = tid + it * 256;      // 512 float4s = 16 rows x 32 float4
        int kr = f >> 5;
        int c4 = (f & 31) << 2;
        float4 v = *(const float4*)&src[(size_t)(k0 + kr) * ld + col0 + c4];
        *(float4*)&T[kr][c4] = v;
    }
}

__device__ __forceinline__ void mm_core(const float (*As)[132],
                                        const float (*Bs)[132],
                                        float acc[8][8], int tx, int ty) {
#pragma unroll
    for (int kk = 0; kk < 16; ++kk) {
        float a[8], b[8];
        *(float4*)&a[0] = *(const float4*)&As[kk][ty * 8];
        *(float4*)&a[4] = *(const float4*)&As[kk][ty * 8 + 4];
        *(float4*)&b[0] = *(const float4*)&Bs[kk][tx * 8];
        *(float4*)&b[4] = *(const float4*)&Bs[kk][tx * 8 + 4];
#pragma unroll
        for (int i = 0; i < 8; ++i)
#pragma unroll
            for (int j = 0; j < 8; ++j)
                acc[i][j] = fmaf(a[i], b[j], acc[i][j]);
    }
}

// ============================ projection GEMM ==============================
// out[m,n] = sum_k X[m_base+m,k] * W[k,n] + bias[n];  X = concat(inp, pe)
// out is chunk-local (row m corresponds to global row m_base+m)
__global__ __launch_bounds__(256) void proj_gemm(
        const float* __restrict__ inp, const float* __restrict__ pe,
        const float* __restrict__ W, const float* __restrict__ bias,
        float* __restrict__ out, int m_base) {
    __shared__ float As[16][132];
    __shared__ float Bs[16][132];
    const int tid = threadIdx.x;
    const int tx = tid & 15, ty = tid >> 4;
    const int m0 = blockIdx.x * 128;
    const int n0 = blockIdx.y * 128;

    float acc[8][8];
#pragma unroll
    for (int i = 0; i < 8; ++i)
#pragma unroll
        for (int j = 0; j < 8; ++j) acc[i][j] = 0.0f;

    for (int k0 = 0; k0 < K2_; k0 += 16) {
        // ---- stage A (virtual concat: inp for k<1024, pe for k>=1024) ----
#pragma unroll
        for (int it = 0; it < 2; ++it) {
            int f  = tid + it * 256;
            int r  = f >> 2;
            int c4 = (f & 3) << 2;
            int gm = m_base + m0 + r;        // global row
            float4 v;
            if (k0 < D_) {
                v = *(const float4*)&inp[(size_t)gm * D_ + k0 + c4];
            } else {
                int s = gm & (S_ - 1);
                v = *(const float4*)&pe[(size_t)s * D_ + (k0 - D_) + c4];
            }
            As[c4 + 0][r] = v.x;
            As[c4 + 1][r] = v.y;
            As[c4 + 2][r] = v.z;
            As[c4 + 3][r] = v.w;
        }
        stage_direct(W, D_, k0, n0, Bs, tid);
        __syncthreads();
        mm_core(As, Bs, acc, tx, ty);
        __syncthreads();
    }

    // epilogue: + bias, float4 stores
    float bv[8];
    *(float4*)&bv[0] = *(const float4*)&bias[n0 + tx * 8];
    *(float4*)&bv[4] = *(const float4*)&bias[n0 + tx * 8 + 4];
#pragma unroll
    for (int i = 0; i < 8; ++i) {
        int m = m0 + ty * 8 + i;             // chunk-local row
        float o[8];
#pragma unroll
        for (int j = 0; j < 8; ++j) o[j] = acc[i][j] + bv[j];
        *(float4*)&out[(size_t)m * D_ + n0 + tx * 8]     = *(float4*)&o[0];
        *(float4*)&out[(size_t)m * D_ + n0 + tx * 8 + 4] = *(float4*)&o[4];
    }
}

// ============================== QK^T GEMM ==================================
// scoresT[bz,i,j] = sum_d K[bz,i,d] * Q[bz,j,d]  (all chunk-local)
__global__ __launch_bounds__(256) void qk_gemm(
        const float* __restrict__ q, const float* __restrict__ k,
        float* __restrict__ scoresT) {
    __shared__ float As[16][132];
    __shared__ float Bs[16][132];
    const int tid = threadIdx.x;
    const int tx = tid & 15, ty = tid >> 4;
    const int b  = blockIdx.z;
    const int i0 = blockIdx.x * 128;
    const int j0 = blockIdx.y * 128;
    const float* Kb = k + (size_t)b * S_ * D_;
    const float* Qb = q + (size_t)b * S_ * D_;

    float acc[8][8];
#pragma unroll
    for (int i = 0; i < 8; ++i)
#pragma unroll
        for (int j = 0; j < 8; ++j) acc[i][j] = 0.0f;

    for (int d0 = 0; d0 < D_; d0 += 16) {
        stage_trans(Kb, D_, i0, d0, As, tid);
        stage_trans(Qb, D_, j0, d0, Bs, tid);
        __syncthreads();
        mm_core(As, Bs, acc, tx, ty);
        __syncthreads();
    }

    float* outb = scoresT + (size_t)b * S_ * S_;
#pragma unroll
    for (int i = 0; i < 8; ++i) {
        int ii = i0 + ty * 8 + i;
        *(float4*)&outb[(size_t)ii * S_ + j0 + tx * 8]     = *(float4*)&acc[i][0];
        *(float4*)&outb[(size_t)ii * S_ + j0 + tx * 8 + 4] = *(float4*)&acc[i][4];
    }
}

// ============================ softmax over q ===============================
// scoresT rows are contiguous in q; softmax each row, then * 1/sqrt(1024)
__global__ __launch_bounds__(256) void softmax_rows(float* __restrict__ scoresT) {
    const size_t row = blockIdx.x;
    float* p = scoresT + row * S_;
    const int tid = threadIdx.x;

    __shared__ float sm[4], ss[4];

    float4 x0 = *(const float4*)&p[tid * 4];
    float4 x1 = *(const float4*)&p[1024 + tid * 4];

    float mx = fmaxf(fmaxf(fmaxf(x0.x, x0.y), fmaxf(x0.z, x0.w)),
                     fmaxf(fmaxf(x1.x, x1.y), fmaxf(x1.z, x1.w)));
#pragma unroll
    for (int o = 32; o > 0; o >>= 1) mx = fmaxf(mx, __shfl_xor(mx, o));
    if ((tid & 63) == 0) sm[tid >> 6] = mx;
    __syncthreads();
    mx = fmaxf(fmaxf(sm[0], sm[1]), fmaxf(sm[2], sm[3]));

    float e[8];
    e[0] = expf(x0.x - mx); e[1] = expf(x0.y - mx);
    e[2] = expf(x0.z - mx); e[3] = expf(x0.w - mx);
    e[4] = expf(x1.x - mx); e[5] = expf(x1.y - mx);
    e[6] = expf(x1.z - mx); e[7] = expf(x1.w - mx);
    float s = e[0] + e[1] + e[2] + e[3] + e[4] + e[5] + e[6] + e[7];
#pragma unroll
    for (int o = 32; o > 0; o >>= 1) s += __shfl_xor(s, o);
    if ((tid & 63) == 0) ss[tid >> 6] = s;
    __syncthreads();
    s = ss[0] + ss[1] + ss[2] + ss[3];

    const float sc = 0.03125f / s;   // (1/sum) * 1/sqrt(1024)
    float4 o0 = make_float4(e[0] * sc, e[1] * sc, e[2] * sc, e[3] * sc);
    float4 o1 = make_float4(e[4] * sc, e[5] * sc, e[6] * sc, e[7] * sc);
    *(float4*)&p[tid * 4]        = o0;
    *(float4*)&p[1024 + tid * 4] = o1;
}

// =============================== attn @ V ==================================
// sa[bz,q,d] = sum_k P[bz,k,q] * V[bz,k,d]; sa pointer pre-offset to chunk
__global__ __launch_bounds__(256) void av_gemm(
        const float* __restrict__ P, const float* __restrict__ V,
        float* __restrict__ sa) {
    __shared__ float As[16][132];
    __shared__ float Bs[16][132];
    const int tid = threadIdx.x;
    const int tx = tid & 15, ty = tid >> 4;
    const int b  = blockIdx.z;
    const int q0 = blockIdx.x * 128;
    const int n0 = blockIdx.y * 128;
    const float* Pb = P + (size_t)b * S_ * S_;
    const float* Vb = V + (size_t)b * S_ * D_;

    float acc[8][8];
#pragma unroll
    for (int i = 0; i < 8; ++i)
#pragma unroll
        for (int j = 0; j < 8; ++j) acc[i][j] = 0.0f;

    for (int k0 = 0; k0 < S_; k0 += 16) {
        stage_direct(Pb, S_, k0, q0, As, tid);
        stage_direct(Vb, D_, k0, n0, Bs, tid);
        __syncthreads();
        mm_core(As, Bs, acc, tx, ty);
        __syncthreads();
    }

    float* outb = sa + (size_t)b * S_ * D_;
#pragma unroll
    for (int i = 0; i < 8; ++i) {
        int qq = q0 + ty * 8 + i;
        *(float4*)&outb[(size_t)qq * D_ + n0 + tx * 8]     = *(float4*)&acc[i][0];
        *(float4*)&outb[(size_t)qq * D_ + n0 + tx * 8 + 4] = *(float4*)&acc[i][4];
    }
}

// ======================== LayerNorm + context sum ==========================
__global__ __launch_bounds__(256) void zero_f(float* __restrict__ p, int n) {
    int i = blockIdx.x * 256 + threadIdx.x;
    if (i < n) p[i] = 0.0f;
}

__global__ __launch_bounds__(256) void ln_ctx(
        const float* __restrict__ sa, const float* __restrict__ gamma,
        const float* __restrict__ beta, float* __restrict__ ctx) {
    const int blk = blockIdx.x;        // 128 blocks: 16 per batch
    const int b   = blk >> 4;
    const int r0  = (blk & 15) * 128;
    const int tid = threadIdx.x;
    const int c   = tid * 4;

    __shared__ float sred[8];

    float g[4], be[4];
    *(float4*)&g[0]  = *(const float4*)&gamma[c];
    *(float4*)&be[0] = *(const float4*)&beta[c];

    float accv[4] = {0.0f, 0.0f, 0.0f, 0.0f};

    for (int r = 0; r < 128; ++r) {
        const float* row = sa + (size_t)(b * S_ + r0 + r) * D_;
        float x[4];
        *(float4*)&x[0] = *(const float4*)&row[c];
        float s  = x[0] + x[1] + x[2] + x[3];
        float s2 = fmaf(x[0], x[0], fmaf(x[1], x[1], fmaf(x[2], x[2], x[3] * x[3])));
#pragma unroll
        for (int o = 32; o > 0; o >>= 1) {
            s  += __shfl_xor(s, o);
            s2 += __shfl_xor(s2, o);
        }
        if ((tid & 63) == 0) { sred[tid >> 6] = s; sred[4 + (tid >> 6)] = s2; }
        __syncthreads();
        float sum   = sred[0] + sred[1] + sred[2] + sred[3];
        float sumsq = sred[4] + sred[5] + sred[6] + sred[7];
        __syncthreads();

        float mu  = sum * (1.0f / (float)D_);
        float var = sumsq * (1.0f / (float)D_) - mu * mu;
        float rs  = rsqrtf(var + 1e-5f);
#pragma unroll
        for (int j = 0; j < 4; ++j)
            accv[j] += (x[j] - mu) * rs * g[j] + be[j];
    }

#pragma unroll
    for (int j = 0; j < 4; ++j)
        atomicAdd(&ctx[b * D_ + c + j], accv[j] * (1.0f / (float)S_));
}

// ================================ launch ===================================
extern "C" void kernel_launch(void* const* d_in, const int* in_sizes, int n_in,
                              void* d_out, int out_size, void* d_ws, size_t ws_size,
                              hipStream_t stream) {
    const float* inp   = (const float*)d_in[0];
    const float* Wq    = (const float*)d_in[1];
    const float* bq    = (const float*)d_in[2];
    const float* Wk    = (const float*)d_in[3];
    const float* bk    = (const float*)d_in[4];
    const float* Wv    = (const float*)d_in[5];
    const float* bv    = (const float*)d_in[6];
    const float* gamma = (const float*)d_in[7];
    const float* beta  = (const float*)d_in[8];
    // d_in[9] = lens (unused by the reference computation)

    // ---- pick chunk size c (batches per chunk) from ws_size ----
    // bytes(c) = 8 MiB (pe) + c * 32 MiB (q/v + k + scoresT)
    const size_t MiB = 1024 * 1024;
    int c = 1;
    if      (ws_size >= 8 * MiB + 8 * 32 * MiB) c = 8;
    else if (ws_size >= 8 * MiB + 4 * 32 * MiB) c = 4;
    else if (ws_size >= 8 * MiB + 2 * 32 * MiB) c = 2;

    float* ws      = (float*)d_ws;
    float* pe      = ws;
    float* bufQV   = pe + (size_t)S_ * D_;                  // c*S_*D_
    float* bufK    = bufQV + (size_t)c * S_ * D_;           // c*S_*D_
    float* scoresT = bufK  + (size_t)c * S_ * D_;           // c*S_*S_

    float* sa  = (float*)d_out;                   // [B,S,D]
    float* ctx = (float*)d_out + (size_t)M_ * D_; // [B,D]

    pe_fill<<<dim3(S_), dim3(256), 0, stream>>>(pe);

    const int nchunk = B_ / c;
    for (int ch = 0; ch < nchunk; ++ch) {
        const int b0     = ch * c;
        const int m_base = b0 * S_;

        // q = X@Wq + bq ; k = X@Wk + bk   (chunk-local outputs)
        proj_gemm<<<dim3(16 * c, 8), dim3(256), 0, stream>>>(inp, pe, Wq, bq, bufQV, m_base);
        proj_gemm<<<dim3(16 * c, 8), dim3(256), 0, stream>>>(inp, pe, Wk, bk, bufK,  m_base);

        // scoresT[b,k,q] = K Q^T
        qk_gemm<<<dim3(16, 16, c), dim3(256), 0, stream>>>(bufQV, bufK, scoresT);

        // softmax over q (contiguous rows), then * 1/32
        softmax_rows<<<dim3(c * S_), dim3(256), 0, stream>>>(scoresT);

        // v = X@Wv + bv (reuse bufQV; q no longer needed)
        proj_gemm<<<dim3(16 * c, 8), dim3(256), 0, stream>>>(inp, pe, Wv, bv, bufQV, m_base);

        // sa[b,q,d] = sum_k P[b,k,q] V[b,k,d]
        av_gemm<<<dim3(16, 8, c), dim3(256), 0, stream>>>(scoresT, bufQV,
                                                          sa + (size_t)b0 * S_ * D_);
    }

    // context = mean over q of LN(sa)
    zero_f<<<dim3(32), dim3(256), 0, stream>>>(ctx, B_ * D_);
    ln_ctx<<<dim3(128), dim3(256), 0, stream>>>(sa, gamma, beta, ctx);
}

// Round 4
// 4236.214 us; speedup vs baseline: 1.0805x; 1.0805x over previous
//
#include <hip/hip_runtime.h>
#include <math.h>

// Problem constants (fixed by setup_inputs: B=8, S=2048, din=dhid=1024)
#define B_   8
#define S_   2048
#define D_   1024
#define M_   (B_ * S_)    // 16384 rows total
#define K2_  (2 * D_)     // 2048 = concat(inp, pe) width
#define BK   32           // GEMM K-step

// ---------------------------------------------------------------------------
// ws layout (floats), chunked by c batches (c chosen from ws_size at launch):
//   pe      [S_][D_]          @ 0
//   bufQV   [c*S_][D_]        q, later v (reused within chunk)
//   bufK    [c*S_][D_]        k
//   scoresT [c][S_][S_]
// bytes = 8 MiB + c * 32 MiB   (c=8 -> 264 MiB ... c=1 -> 40 MiB)
// ---------------------------------------------------------------------------

// ============================ pe table (float64) ===========================
// pow -> exp2 (fp64): a = s * 10000^(-2(j//2)/1024) = s * exp2(-ex*log2(1e4))
__global__ __launch_bounds__(256) void pe_fill(float* __restrict__ pe) {
    const int s  = blockIdx.x;
    const int j0 = threadIdx.x * 4;
    const double L2_1E4 = 13.287712379549449;   // log2(10000)
#pragma unroll
    for (int e = 0; e < 4; ++e) {
        int j = j0 + e;
        double ex = (double)(2 * (j >> 1)) / (double)D_;
        double a  = (double)s * exp2(-ex * L2_1E4);
        float val;
        if (s == 0) val = 0.0f;
        else        val = (j & 1) ? (float)cos(a) : (float)sin(a);
        pe[s * D_ + j] = val;
    }
}

// ======================= shared GEMM building blocks =======================
// Tile: 128x128, BK=32, 256 threads, 8x8 micro-tile per thread.
// Fragment layout: thread covers rows {ty*4..+3, 64+ty*4..+3} and cols
// {tx*4..+3, 64+tx*4..+3} -> all LDS frag reads are 16 lanes x 16B
// CONTIGUOUS (256B) = bank-conflict-free (was 4-way at tx*8).
// As/Bs: [BK][132] (pad 4 floats keeps float4 alignment, rotates banks/row)

__device__ __forceinline__ void stage_trans(const float* __restrict__ src,
                                            int ld, int row0, int k0,
                                            float (*T)[132], int tid) {
    // src rows are the M/N dim, cols the K dim -> store transposed T[k][row]
#pragma unroll
    for (int it = 0; it < 4; ++it) {
        int f  = tid + it * 256;      // 1024 float4s = 128 rows x 8 float4
        int r  = f >> 3;
        int c4 = (f & 7) << 2;
        float4 v = *(const float4*)&src[(size_t)(row0 + r) * ld + k0 + c4];
        T[c4 + 0][r] = v.x;
        T[c4 + 1][r] = v.y;
        T[c4 + 2][r] = v.z;
        T[c4 + 3][r] = v.w;
    }
}

__device__ __forceinline__ void stage_direct(const float* __restrict__ src,
                                             int ld, int k0, int col0,
                                             float (*T)[132], int tid) {
    // src rows are the K dim -> straight copy T[k][col]
#pragma unroll
    for (int it = 0; it < 4; ++it) {
        int f  = tid + it * 256;      // 1024 float4s = 32 rows x 32 float4
        int kr = f >> 5;
        int c4 = (f & 31) << 2;
        float4 v = *(const float4*)&src[(size_t)(k0 + kr) * ld + col0 + c4];
        *(float4*)&T[kr][c4] = v;
    }
}

__device__ __forceinline__ void mm_core(const float (*As)[132],
                                        const float (*Bs)[132],
                                        float acc[8][8], int tx, int ty) {
#pragma unroll
    for (int kk = 0; kk < BK; ++kk) {
        float a[8], b[8];
        *(float4*)&a[0] = *(const float4*)&As[kk][ty * 4];
        *(float4*)&a[4] = *(const float4*)&As[kk][64 + ty * 4];
        *(float4*)&b[0] = *(const float4*)&Bs[kk][tx * 4];
        *(float4*)&b[4] = *(const float4*)&Bs[kk][64 + tx * 4];
#pragma unroll
        for (int i = 0; i < 8; ++i)
#pragma unroll
            for (int j = 0; j < 8; ++j)
                acc[i][j] = fmaf(a[i], b[j], acc[i][j]);
    }
}

// row index helper for the split micro-tile
__device__ __forceinline__ int frag_idx(int t4, int h, int e) {
    return h == 0 ? t4 * 4 + e : 64 + t4 * 4 + e;
}

// ============================ projection GEMM ==============================
// out[m,n] = sum_k X[m_base+m,k] * W[k,n] + bias[n];  X = concat(inp, pe)
__global__ __launch_bounds__(256) void proj_gemm(
        const float* __restrict__ inp, const float* __restrict__ pe,
        const float* __restrict__ W, const float* __restrict__ bias,
        float* __restrict__ out, int m_base) {
    __shared__ float As[BK][132];
    __shared__ float Bs[BK][132];
    const int tid = threadIdx.x;
    const int tx = tid & 15, ty = tid >> 4;
    const int m0 = blockIdx.x * 128;
    const int n0 = blockIdx.y * 128;

    float acc[8][8];
#pragma unroll
    for (int i = 0; i < 8; ++i)
#pragma unroll
        for (int j = 0; j < 8; ++j) acc[i][j] = 0.0f;

    for (int k0 = 0; k0 < K2_; k0 += BK) {
        // ---- stage A (virtual concat: inp for k<1024, pe for k>=1024) ----
#pragma unroll
        for (int it = 0; it < 4; ++it) {
            int f  = tid + it * 256;
            int r  = f >> 3;
            int c4 = (f & 7) << 2;
            int gm = m_base + m0 + r;        // global row
            float4 v;
            if (k0 < D_) {
                v = *(const float4*)&inp[(size_t)gm * D_ + k0 + c4];
            } else {
                int s = gm & (S_ - 1);
                v = *(const float4*)&pe[(size_t)s * D_ + (k0 - D_) + c4];
            }
            As[c4 + 0][r] = v.x;
            As[c4 + 1][r] = v.y;
            As[c4 + 2][r] = v.z;
            As[c4 + 3][r] = v.w;
        }
        stage_direct(W, D_, k0, n0, Bs, tid);
        __syncthreads();
        mm_core(As, Bs, acc, tx, ty);
        __syncthreads();
    }

    // epilogue: + bias, two float4 stores per row (256B-contiguous per wave)
    float bv[8];
    *(float4*)&bv[0] = *(const float4*)&bias[n0 + tx * 4];
    *(float4*)&bv[4] = *(const float4*)&bias[n0 + 64 + tx * 4];
#pragma unroll
    for (int ih = 0; ih < 2; ++ih)
#pragma unroll
    for (int ii = 0; ii < 4; ++ii) {
        int i = ih * 4 + ii;
        int m = m0 + frag_idx(ty, ih, ii);
        float o[8];
#pragma unroll
        for (int j = 0; j < 8; ++j) o[j] = acc[i][j] + bv[j];
        *(float4*)&out[(size_t)m * D_ + n0 + tx * 4]      = *(float4*)&o[0];
        *(float4*)&out[(size_t)m * D_ + n0 + 64 + tx * 4] = *(float4*)&o[4];
    }
}

// ============================== QK^T GEMM ==================================
// scoresT[bz,i,j] = sum_d K[bz,i,d] * Q[bz,j,d]  (all chunk-local)
__global__ __launch_bounds__(256) void qk_gemm(
        const float* __restrict__ q, const float* __restrict__ k,
        float* __restrict__ scoresT) {
    __shared__ float As[BK][132];
    __shared__ float Bs[BK][132];
    const int tid = threadIdx.x;
    const int tx = tid & 15, ty = tid >> 4;
    const int b  = blockIdx.z;
    const int i0 = blockIdx.x * 128;
    const int j0 = blockIdx.y * 128;
    const float* Kb = k + (size_t)b * S_ * D_;
    const float* Qb = q + (size_t)b * S_ * D_;

    float acc[8][8];
#pragma unroll
    for (int i = 0; i < 8; ++i)
#pragma unroll
        for (int j = 0; j < 8; ++j) acc[i][j] = 0.0f;

    for (int d0 = 0; d0 < D_; d0 += BK) {
        stage_trans(Kb, D_, i0, d0, As, tid);
        stage_trans(Qb, D_, j0, d0, Bs, tid);
        __syncthreads();
        mm_core(As, Bs, acc, tx, ty);
        __syncthreads();
    }

    float* outb = scoresT + (size_t)b * S_ * S_;
#pragma unroll
    for (int ih = 0; ih < 2; ++ih)
#pragma unroll
    for (int ii = 0; ii < 4; ++ii) {
        int i  = ih * 4 + ii;
        int ir = i0 + frag_idx(ty, ih, ii);
        *(float4*)&outb[(size_t)ir * S_ + j0 + tx * 4]      = *(float4*)&acc[i][0];
        *(float4*)&outb[(size_t)ir * S_ + j0 + 64 + tx * 4] = *(float4*)&acc[i][4];
    }
}

// ============================ softmax over q ===============================
__global__ __launch_bounds__(256) void softmax_rows(float* __restrict__ scoresT) {
    const size_t row = blockIdx.x;
    float* p = scoresT + row * S_;
    const int tid = threadIdx.x;

    __shared__ float sm[4], ss[4];

    float4 x0 = *(const float4*)&p[tid * 4];
    float4 x1 = *(const float4*)&p[1024 + tid * 4];

    float mx = fmaxf(fmaxf(fmaxf(x0.x, x0.y), fmaxf(x0.z, x0.w)),
                     fmaxf(fmaxf(x1.x, x1.y), fmaxf(x1.z, x1.w)));
#pragma unroll
    for (int o = 32; o > 0; o >>= 1) mx = fmaxf(mx, __shfl_xor(mx, o));
    if ((tid & 63) == 0) sm[tid >> 6] = mx;
    __syncthreads();
    mx = fmaxf(fmaxf(sm[0], sm[1]), fmaxf(sm[2], sm[3]));

    float e[8];
    e[0] = expf(x0.x - mx); e[1] = expf(x0.y - mx);
    e[2] = expf(x0.z - mx); e[3] = expf(x0.w - mx);
    e[4] = expf(x1.x - mx); e[5] = expf(x1.y - mx);
    e[6] = expf(x1.z - mx); e[7] = expf(x1.w - mx);
    float s = e[0] + e[1] + e[2] + e[3] + e[4] + e[5] + e[6] + e[7];
#pragma unroll
    for (int o = 32; o > 0; o >>= 1) s += __shfl_xor(s, o);
    if ((tid & 63) == 0) ss[tid >> 6] = s;
    __syncthreads();
    s = ss[0] + ss[1] + ss[2] + ss[3];

    const float sc = 0.03125f / s;   // (1/sum) * 1/sqrt(1024)
    float4 o0 = make_float4(e[0] * sc, e[1] * sc, e[2] * sc, e[3] * sc);
    float4 o1 = make_float4(e[4] * sc, e[5] * sc, e[6] * sc, e[7] * sc);
    *(float4*)&p[tid * 4]        = o0;
    *(float4*)&p[1024 + tid * 4] = o1;
}

// =============================== attn @ V ==================================
// sa[bz,q,d] = sum_k P[bz,k,q] * V[bz,k,d]; sa pointer pre-offset to chunk
__global__ __launch_bounds__(256) void av_gemm(
        const float* __restrict__ P, const float* __restrict__ V,
        float* __restrict__ sa) {
    __shared__ float As[BK][132];
    __shared__ float Bs[BK][132];
    const int tid = threadIdx.x;
    const int tx = tid & 15, ty = tid >> 4;
    const int b  = blockIdx.z;
    const int q0 = blockIdx.x * 128;
    const int n0 = blockIdx.y * 128;
    const float* Pb = P + (size_t)b * S_ * S_;
    const float* Vb = V + (size_t)b * S_ * D_;

    float acc[8][8];
#pragma unroll
    for (int i = 0; i < 8; ++i)
#pragma unroll
        for (int j = 0; j < 8; ++j) acc[i][j] = 0.0f;

    for (int k0 = 0; k0 < S_; k0 += BK) {
        stage_direct(Pb, S_, k0, q0, As, tid);
        stage_direct(Vb, D_, k0, n0, Bs, tid);
        __syncthreads();
        mm_core(As, Bs, acc, tx, ty);
        __syncthreads();
    }

    float* outb = sa + (size_t)b * S_ * D_;
#pragma unroll
    for (int ih = 0; ih < 2; ++ih)
#pragma unroll
    for (int ii = 0; ii < 4; ++ii) {
        int i  = ih * 4 + ii;
        int qq = q0 + frag_idx(ty, ih, ii);
        *(float4*)&outb[(size_t)qq * D_ + n0 + tx * 4]      = *(float4*)&acc[i][0];
        *(float4*)&outb[(size_t)qq * D_ + n0 + 64 + tx * 4] = *(float4*)&acc[i][4];
    }
}

// ======================== LayerNorm + context sum ==========================
__global__ __launch_bounds__(256) void zero_f(float* __restrict__ p, int n) {
    int i = blockIdx.x * 256 + threadIdx.x;
    if (i < n) p[i] = 0.0f;
}

// 1024 blocks x 16 rows (was 128 x 128): full machine + 8x less serial chain
__global__ __launch_bounds__(256) void ln_ctx(
        const float* __restrict__ sa, const float* __restrict__ gamma,
        const float* __restrict__ beta, float* __restrict__ ctx) {
    const int row0 = blockIdx.x * 16;          // 16384/16 = 1024 blocks
    const int b    = row0 >> 11;               // 2048 rows per batch
    const int tid  = threadIdx.x;
    const int c    = tid * 4;

    __shared__ float sred[8];

    float g[4], be[4];
    *(float4*)&g[0]  = *(const float4*)&gamma[c];
    *(float4*)&be[0] = *(const float4*)&beta[c];

    float accv[4] = {0.0f, 0.0f, 0.0f, 0.0f};

    for (int r = 0; r < 16; ++r) {
        const float* row = sa + (size_t)(row0 + r) * D_;
        float x[4];
        *(float4*)&x[0] = *(const float4*)&row[c];
        float s  = x[0] + x[1] + x[2] + x[3];
        float s2 = fmaf(x[0], x[0], fmaf(x[1], x[1], fmaf(x[2], x[2], x[3] * x[3])));
#pragma unroll
        for (int o = 32; o > 0; o >>= 1) {
            s  += __shfl_xor(s, o);
            s2 += __shfl_xor(s2, o);
        }
        if ((tid & 63) == 0) { sred[tid >> 6] = s; sred[4 + (tid >> 6)] = s2; }
        __syncthreads();
        float sum   = sred[0] + sred[1] + sred[2] + sred[3];
        float sumsq = sred[4] + sred[5] + sred[6] + sred[7];
        __syncthreads();

        float mu  = sum * (1.0f / (float)D_);
        float var = sumsq * (1.0f / (float)D_) - mu * mu;
        float rs  = rsqrtf(var + 1e-5f);
#pragma unroll
        for (int j = 0; j < 4; ++j)
            accv[j] += (x[j] - mu) * rs * g[j] + be[j];
    }

#pragma unroll
    for (int j = 0; j < 4; ++j)
        atomicAdd(&ctx[b * D_ + c + j], accv[j] * (1.0f / (float)S_));
}

// ================================ launch ===================================
extern "C" void kernel_launch(void* const* d_in, const int* in_sizes, int n_in,
                              void* d_out, int out_size, void* d_ws, size_t ws_size,
                              hipStream_t stream) {
    const float* inp   = (const float*)d_in[0];
    const float* Wq    = (const float*)d_in[1];
    const float* bq    = (const float*)d_in[2];
    const float* Wk    = (const float*)d_in[3];
    const float* bk    = (const float*)d_in[4];
    const float* Wv    = (const float*)d_in[5];
    const float* bv    = (const float*)d_in[6];
    const float* gamma = (const float*)d_in[7];
    const float* beta  = (const float*)d_in[8];
    // d_in[9] = lens (unused by the reference computation)

    // ---- pick chunk size c (batches per chunk) from ws_size ----
    // bytes(c) = 8 MiB (pe) + c * 32 MiB (q/v + k + scoresT)
    const size_t MiB = 1024 * 1024;
    int c = 1;
    if      (ws_size >= 8 * MiB + 8 * 32 * MiB) c = 8;
    else if (ws_size >= 8 * MiB + 4 * 32 * MiB) c = 4;
    else if (ws_size >= 8 * MiB + 2 * 32 * MiB) c = 2;

    float* ws      = (float*)d_ws;
    float* pe      = ws;
    float* bufQV   = pe + (size_t)S_ * D_;                  // c*S_*D_
    float* bufK    = bufQV + (size_t)c * S_ * D_;           // c*S_*D_
    float* scoresT = bufK  + (size_t)c * S_ * D_;           // c*S_*S_

    float* sa  = (float*)d_out;                   // [B,S,D]
    float* ctx = (float*)d_out + (size_t)M_ * D_; // [B,D]

    pe_fill<<<dim3(S_), dim3(256), 0, stream>>>(pe);

    const int nchunk = B_ / c;
    for (int ch = 0; ch < nchunk; ++ch) {
        const int b0     = ch * c;
        const int m_base = b0 * S_;

        // q = X@Wq + bq ; k = X@Wk + bk   (chunk-local outputs)
        proj_gemm<<<dim3(16 * c, 8), dim3(256), 0, stream>>>(inp, pe, Wq, bq, bufQV, m_base);
        proj_gemm<<<dim3(16 * c, 8), dim3(256), 0, stream>>>(inp, pe, Wk, bk, bufK,  m_base);

        // scoresT[b,k,q] = K Q^T
        qk_gemm<<<dim3(16, 16, c), dim3(256), 0, stream>>>(bufQV, bufK, scoresT);

        // softmax over q (contiguous rows), then * 1/32
        softmax_rows<<<dim3(c * S_), dim3(256), 0, stream>>>(scoresT);

        // v = X@Wv + bv (reuse bufQV; q no longer needed)
        proj_gemm<<<dim3(16 * c, 8), dim3(256), 0, stream>>>(inp, pe, Wv, bv, bufQV, m_base);

        // sa[b,q,d] = sum_k P[b,k,q] V[b,k,d]
        av_gemm<<<dim3(16, 8, c), dim3(256), 0, stream>>>(scoresT, bufQV,
                                                          sa + (size_t)b0 * S_ * D_);
    }

    // context = mean over q of LN(sa)
    zero_f<<<dim3(32), dim3(256), 0, stream>>>(ctx, B_ * D_);
    ln_ctx<<<dim3(1024), dim3(256), 0, stream>>>(sa, gamma, beta, ctx);
}